// Round 7
// baseline (247.206 us; speedup 1.0000x reference)
//
#include <hip/hip_runtime.h>
#include <cmath>

#define NN 50000
#define NP 50048
#define NE 800000
#define CD 40
#define NEG_SLOPE 0.2f
#define NITEMS (NE + NN)   // edges + self-loops
#define CHUNK 2048
#define NCH 416            // ceil(NITEMS / CHUNK)
#define NBKT 391           // node buckets of 128 (covers 50048)
#define BCAP 3072          // bucket capacity (mean 2174, +19 sigma)
#define GB1 782            // gemm blocks, 64 rows each (NP/64)
#define TB1 (3 * 64 * 256)
#define TB2 (3 * 64 * 64)
#define WPB 240            // W-pack blocks ((TB1+TB2)/256)

typedef __attribute__((ext_vector_type(8))) short s16x8;   // 8 bf16
typedef __attribute__((ext_vector_type(4))) float f32x4;   // 4 fp32 acc
typedef __attribute__((ext_vector_type(2))) float f32x2;   // packed-math pair

__device__ __forceinline__ f32x2 pk_fma(f32x2 a, f32x2 b, f32x2 c) {
#if __has_builtin(__builtin_elementwise_fma)
  return __builtin_elementwise_fma(a, b, c);
#else
  f32x2 r; r[0] = fmaf(a[0], b[0], c[0]); r[1] = fmaf(a[1], b[1], c[1]); return r;
#endif
}
__device__ __forceinline__ f32x2 pk_max(f32x2 a, f32x2 b) {
#if __has_builtin(__builtin_elementwise_max)
  return __builtin_elementwise_max(a, b);
#else
  f32x2 r; r[0] = fmaxf(a[0], b[0]); r[1] = fmaxf(a[1], b[1]); return r;
#endif
}

__device__ __forceinline__ short f2bf(float x) {  // RNE, finite
  unsigned u = __builtin_bit_cast(unsigned, x);
  u += 0x7fffu + ((u >> 16) & 1u);
  return (short)(u >> 16);
}
__device__ __forceinline__ unsigned pack2(float lo, float hi) {
  return (unsigned)(unsigned short)f2bf(lo) | ((unsigned)(unsigned short)f2bf(hi) << 16);
}
__device__ __forceinline__ float bf2f_lo(unsigned v) {
  return __builtin_bit_cast(float, v << 16);
}
__device__ __forceinline__ float bf2f_hi(unsigned v) {
  return __builtin_bit_cast(float, v & 0xffff0000u);
}
__device__ __forceinline__ void unp8(uint4 v, f32x2* f) {
  f[0] = (f32x2){bf2f_lo(v.x), bf2f_hi(v.x)};
  f[1] = (f32x2){bf2f_lo(v.y), bf2f_hi(v.y)};
  f[2] = (f32x2){bf2f_lo(v.z), bf2f_hi(v.z)};
  f[3] = (f32x2){bf2f_lo(v.w), bf2f_hi(v.w)};
}
__device__ __forceinline__ uint4 zero4() {
  uint4 z; z.x = 0u; z.y = 0u; z.z = 0u; z.w = 0u; return z;
}

// ====== prep_bin: W frag-pack (blocks 0..239) | edge binning (blocks 240..) ======
__global__ __launch_bounds__(256) void prep_bin(const float* __restrict__ W1l,
                                                const float* __restrict__ W1r,
                                                const float* __restrict__ L1,
                                                const float* __restrict__ W2l,
                                                const float* __restrict__ W2r,
                                                const float* __restrict__ L2,
                                                short* __restrict__ Wp1,
                                                short* __restrict__ Wp2,
                                                const int* __restrict__ ei,
                                                float* __restrict__ outE,
                                                int* __restrict__ gcur,
                                                unsigned* __restrict__ rec) {
  const int tid = threadIdx.x;
  if (blockIdx.x < WPB) {  // W pack: [kb][w][t][lane][j]
    int e = blockIdx.x * 256 + tid;
    if (e < TB1) {  // layer 1: K=256, OC=64, src [256][64]
      int kb = e / 6144, r = e % 6144;
      int w = r / 2048, r2 = r % 2048;
      int t = r2 / 512, r3 = r2 % 512;
      int lane = r3 / 8, j = r3 % 8;
      int n = t * 16 + (lane & 15);
      int k = kb * 32 + (lane >> 4) * 8 + j;
      const float* W = (w == 0) ? W1l : (w == 1) ? W1r : L1;
      Wp1[e] = f2bf(W[k * 64 + n]);
    } else {  // layer 2: K=64, OC=40 pad 64
      e -= TB1;
      int kb = e / 6144, r = e % 6144;
      int w = r / 2048, r2 = r % 2048;
      int t = r2 / 512, r3 = r2 % 512;
      int lane = r3 / 8, j = r3 % 8;
      int n = t * 16 + (lane & 15);
      int k = kb * 32 + (lane >> 4) * 8 + j;
      const float* W = (w == 0) ? W2l : (w == 1) ? W2r : L2;
      Wp2[e] = (n < 40) ? f2bf(W[k * 40 + n]) : (short)0;
    }
    return;
  }
  // ---- Phase A ----
  __shared__ unsigned sorted[CHUNK];
  __shared__ int hist[512];
  __shared__ int bcur[512];
  __shared__ int gbase[512];
  const int base = (blockIdx.x - WPB) * CHUNK;
  for (int t = tid; t < 512; t += 256) { hist[t] = 0; bcur[t] = 0; gbase[t] = 0; }
  __syncthreads();
  unsigned key[CHUNK / 256];
#pragma unroll
  for (int u = 0; u < CHUNK / 256; ++u) {
    const int j = base + u * 256 + tid;
    unsigned k = 0xFFFFFFFFu;
    if (j < NITEMS) {
      int s, d;
      if (j < NE) {
        s = ei[j]; d = ei[NE + j];
        outE[j] = (float)s; outE[NE + j] = (float)d;
      } else {
        s = j - NE; d = s;
      }
      k = ((unsigned)d << 16) | (unsigned)s;
      atomicAdd(&hist[k >> 23], 1);
    }
    key[u] = k;
  }
  __syncthreads();
  if (tid < 64) {  // exclusive scan hist[0..511], one wave
    int carry = 0;
#pragma unroll
    for (int c = 0; c < 8; ++c) {
      int v = hist[c * 64 + tid];
      int inc = v;
#pragma unroll
      for (int off = 1; off < 64; off <<= 1) {
        int tt = __shfl_up(inc, off, 64);
        if (tid >= off) inc += tt;
      }
      hist[c * 64 + tid] = carry + inc - v;
      carry += __shfl(inc, 63, 64);
    }
  }
  __syncthreads();
#pragma unroll
  for (int u = 0; u < CHUNK / 256; ++u) {
    const unsigned k = key[u];
    if (k != 0xFFFFFFFFu) {
      const int b = k >> 23;
      sorted[hist[b] + atomicAdd(&bcur[b], 1)] = k;
    }
  }
  __syncthreads();
  for (int t = tid; t < NBKT; t += 256) {
    const int c = bcur[t];
    if (c > 0) gbase[t] = atomicAdd(&gcur[t], c);
  }
  __syncthreads();
  const int cnt = min(CHUNK, NITEMS - base);
  for (int i = tid; i < cnt; i += 256) {
    const unsigned k = sorted[i];
    const int b = k >> 23;
    const int p = gbase[b] + (i - hist[b]);
    if (p < BCAP) rec[(size_t)b * BCAP + p] = k;
  }
}

// ================= gemm1 body: 64 rows/block, 16 rows/wave =================
// Round-2 form: fp32 A loads + f2bf repack + explicit one-kb-ahead prefetch.
// (Round-3's bf16 direct-A variant collapsed to 48 VGPR and de-pipelined:
// 166us at ~1% VALU/MFMA util. Do not remove the prefetch structure.)
__device__ __forceinline__ void gemm1_body(int bid, const float* __restrict__ X,
                                           const short* __restrict__ Wp,
                                           const float* __restrict__ B0,
                                           const float* __restrict__ B1,
                                           const float* __restrict__ B2,
                                           unsigned short* __restrict__ Y0,
                                           unsigned short* __restrict__ Y1,
                                           unsigned short* __restrict__ Y2) {
  const int lane = threadIdx.x & 63;
  const int wave = threadIdx.x >> 6;
  const int r0 = bid * 64 + wave * 16;
  const int m = lane & 15;
  const int q = lane >> 4;
  f32x4 acc[3][4] = {};
  const float* a0 = X + (size_t)min(r0 + m, NN - 1) * 256 + q * 8;
  const short* bp = Wp + lane * 8;
  float4 v0 = *reinterpret_cast<const float4*>(a0);
  float4 v1 = *reinterpret_cast<const float4*>(a0 + 4);
#pragma unroll
  for (int kb = 0; kb < 8; ++kb) {
    s16x8 bf[12];
#pragma unroll
    for (int i = 0; i < 12; ++i)  // 12 independent loads, batched
      bf[i] = *reinterpret_cast<const s16x8*>(bp + (size_t)(kb * 12 + i) * 512);
    s16x8 af;
    af[0] = f2bf(v0.x); af[1] = f2bf(v0.y); af[2] = f2bf(v0.z); af[3] = f2bf(v0.w);
    af[4] = f2bf(v1.x); af[5] = f2bf(v1.y); af[6] = f2bf(v1.z); af[7] = f2bf(v1.w);
    if (kb < 7) {  // prefetch next A step before the MFMA burst
      v0 = *reinterpret_cast<const float4*>(a0 + (kb + 1) * 32);
      v1 = *reinterpret_cast<const float4*>(a0 + (kb + 1) * 32 + 4);
    }
#pragma unroll
    for (int i = 0; i < 12; ++i)
      acc[i >> 2][i & 3] = __builtin_amdgcn_mfma_f32_16x16x32_bf16(
          af, bf[i], acc[i >> 2][i & 3], 0, 0, 0);
  }
#pragma unroll
  for (int w = 0; w < 3; ++w) {
    const float* B = (w == 0) ? B0 : (w == 1) ? B1 : B2;
    unsigned short* Y = (w == 0) ? Y0 : (w == 1) ? Y1 : Y2;
#pragma unroll
    for (int t = 0; t < 4; ++t) {
      const int c = t * 16 + m;
      const float bv = B[c];
#pragma unroll
      for (int rg = 0; rg < 4; ++rg) {
        const int row = r0 + q * 4 + rg;
        if (row < NN)
          Y[(size_t)row * 64 + c] = (unsigned short)f2bf(acc[w][t][rg] + bv);
      }
    }
  }
}

// ====== build_gemm1: gemm1 (blocks 0..781) | CSR Phase B (blocks 782..1172) ======
// launch_bounds (256,3): gemm phase is L2-latency bound at 2 waves/SIMD;
// fits without spill, +50% latency hiding (round-5 verified, part of -10us).
__global__ __launch_bounds__(256, 3) void build_gemm1(
    const float* __restrict__ X, const short* __restrict__ Wp1,
    const float* __restrict__ B0, const float* __restrict__ B1,
    const float* __restrict__ B2, unsigned short* __restrict__ Y0,
    unsigned short* __restrict__ Y1, unsigned short* __restrict__ Y2,
    const int* __restrict__ gcur, const unsigned* __restrict__ rec,
    int* __restrict__ offsets, unsigned short* __restrict__ csr16) {
  if (blockIdx.x < GB1) {
    gemm1_body(blockIdx.x, X, Wp1, B0, B1, B2, Y0, Y1, Y2);
    return;
  }
  const int b = blockIdx.x - GB1;
  const int tid = threadIdx.x;
  __shared__ unsigned recs[BCAP];
  __shared__ int red[256];
  __shared__ int cnt[128];
  __shared__ int sc[128];
  __shared__ int cur[128];
  int acc = 0;
  for (int t = tid; t < NBKT; t += 256)
    if (t < b) acc += gcur[t];
  red[tid] = acc;
  __syncthreads();
#pragma unroll
  for (int off = 128; off >= 1; off >>= 1) {
    if (tid < off) red[tid] += red[tid + off];
    __syncthreads();
  }
  const int base = red[0];
  const int Tb = min(gcur[b], BCAP);
  if (tid < 128) cnt[tid] = 0;
  __syncthreads();
  for (int i = tid; i < Tb; i += 256) {
    const unsigned k = rec[(size_t)b * BCAP + i];
    recs[i] = k;
    atomicAdd(&cnt[(k >> 16) & 127], 1);
  }
  __syncthreads();
  if (tid < 128) sc[tid] = cnt[tid];
  __syncthreads();
#pragma unroll
  for (int off = 1; off < 128; off <<= 1) {
    int v = (tid < 128 && tid >= off) ? sc[tid - off] : 0;
    __syncthreads();
    if (tid < 128) sc[tid] += v;
    __syncthreads();
  }
  if (tid < 128) {
    const int n = b * 128 + tid;
    if (n < NN) offsets[n + 1] = base + sc[tid];
    cur[tid] = sc[tid] - cnt[tid];
  }
  if (b == 0 && tid == 0) {
    offsets[0] = 0;
#pragma unroll
    for (int i = 0; i < 8; ++i) csr16[NITEMS + i] = 0;  // pad: agg reads 2 ahead
  }
  __syncthreads();
  for (int i = tid; i < Tb; i += 256) {
    const unsigned k = recs[i];
    const int p = atomicAdd(&cur[(k >> 16) & 127], 1);
    csr16[base + p] = (unsigned short)(k & 0xFFFFu);
  }
}

// ============ gemm2: Hb bf16 [NP][64] @ Wp2, 64 rows/block ============
__global__ __launch_bounds__(256, 2) void gemm2(const short* __restrict__ Xb,
                                                const short* __restrict__ Wp,
                                                const float* __restrict__ B0,
                                                const float* __restrict__ B1,
                                                const float* __restrict__ B2,
                                                unsigned short* __restrict__ Y0,
                                                unsigned short* __restrict__ Y1,
                                                unsigned short* __restrict__ Y2) {
  const int lane = threadIdx.x & 63;
  const int wave = threadIdx.x >> 6;
  const int r0 = blockIdx.x * 64 + wave * 16;
  const int m = lane & 15;
  const int q = lane >> 4;
  f32x4 acc[3][3] = {};
  const short* a0 = Xb + (size_t)(r0 + m) * 64 + q * 8;
  const short* bp = Wp + lane * 8;
#pragma unroll
  for (int kb = 0; kb < 2; ++kb) {
    s16x8 bf[9];
#pragma unroll
    for (int w = 0; w < 3; ++w)
#pragma unroll
      for (int t = 0; t < 3; ++t)
        bf[w * 3 + t] =
            *reinterpret_cast<const s16x8*>(bp + (size_t)(kb * 12 + w * 4 + t) * 512);
    const s16x8 af = *reinterpret_cast<const s16x8*>(a0 + kb * 32);
#pragma unroll
    for (int w = 0; w < 3; ++w)
#pragma unroll
      for (int t = 0; t < 3; ++t)
        acc[w][t] = __builtin_amdgcn_mfma_f32_16x16x32_bf16(af, bf[w * 3 + t],
                                                            acc[w][t], 0, 0, 0);
  }
#pragma unroll
  for (int w = 0; w < 3; ++w) {
    const float* B = (w == 0) ? B0 : (w == 1) ? B1 : B2;
    unsigned short* Y = (w == 0) ? Y0 : (w == 1) ? Y1 : Y2;
#pragma unroll
    for (int t = 0; t < 3; ++t) {
      const int c = t * 16 + m;
      if (c < 40) {
        const float bv = B[c];
#pragma unroll
        for (int rg = 0; rg < 4; ++rg) {
          const int row = r0 + q * 4 + rg;
          if (row < NN)
            Y[(size_t)row * 64 + c] = (unsigned short)f2bf(acc[w][t][rg] + bv);
        }
      }
    }
  }
}

// ====== GATv2 aggregation: 8 NODES per wave (round-5 verified form) ======
// Group g owns node gid (sequential -> coalesced per-node I/O). Per-lane A2
// is the complete sum for its node's dims; no cross-group merge. csr padded
// (+8) so the 2-ahead index prefetch needs no clamps. Independent per-node
// loads (XLIN row, bias, att) are hoisted ABOVE the gather loop for free
// latency overlap. Single-edge/iter pipeline: round-6's 2-edge MLP variant
// regressed (+8us) -> per-lane MLP is not the limiter; keep depth-1.
template <int OC, bool FINAL>
__global__ __launch_bounds__(256) void gat_agg(const unsigned short* __restrict__ XL,
                                               const unsigned short* __restrict__ XR,
                                               const unsigned short* __restrict__ XLIN,
                                               const float* __restrict__ att,
                                               const float* __restrict__ bias,
                                               const int* __restrict__ offsets,
                                               const unsigned short* __restrict__ csr,
                                               float* __restrict__ out,
                                               unsigned short* __restrict__ outb) {
  const int lane = threadIdx.x & 63;
  const int g = lane >> 3;          // node slot within wave
  const int l = lane & 7;           // dim slot (dims 8l..8l+7)
  const int wv = threadIdx.x >> 6;
  const int gid = (blockIdx.x * 4 + wv) * 8 + g;
  const int d = min(gid, NN - 1);
  constexpr bool FULLW = (OC >= 64);
  const bool dimok = FULLW || (8 * l < OC);

  const int beg = offsets[d];
  int end = offsets[d + 1];
  if (gid >= NN) end = beg;         // dead slots: zero iterations
  const int deg = end - beg;
  int mdeg = deg;                   // wave-max degree = loop bound
  mdeg = max(mdeg, __shfl_xor(mdeg, 8, 64));
  mdeg = max(mdeg, __shfl_xor(mdeg, 16, 64));
  mdeg = max(mdeg, __shfl_xor(mdeg, 32, 64));

  f32x2 a2[4] = {};
  float b[8] = {};
  if (dimok) {
    const float4 t0 = *reinterpret_cast<const float4*>(&att[8 * l]);
    const float4 t1 = *reinterpret_cast<const float4*>(&att[8 * l + 4]);
    a2[0] = (f32x2){t0.x, t0.y}; a2[1] = (f32x2){t0.z, t0.w};
    a2[2] = (f32x2){t1.x, t1.y}; a2[3] = (f32x2){t1.z, t1.w};
    const float4 b0 = *reinterpret_cast<const float4*>(&bias[8 * l]);
    const float4 b1 = *reinterpret_cast<const float4*>(&bias[8 * l + 4]);
    b[0] = b0.x; b[1] = b0.y; b[2] = b0.z; b[3] = b0.w;
    b[4] = b1.x; b[5] = b1.y; b[6] = b1.z; b[7] = b1.w;
  }
  f32x2 xr2[4];
  unp8(dimok ? *reinterpret_cast<const uint4*>(XR + (size_t)d * 64 + 8 * l) : zero4(),
       xr2);
  // hoist the (independent) XLIN row load above the gather loop
  const uint4 xlin_raw =
      dimok ? *reinterpret_cast<const uint4*>(XLIN + (size_t)d * 64 + 8 * l) : zero4();

  const unsigned short* XLl = XL + 8 * l;
  float D = 0.f;
  f32x2 A2[4] = {};
  const f32x2 ns = (f32x2){NEG_SLOPE, NEG_SLOPE};
  // pipeline: data one ahead, index two ahead (padded csr, no clamps)
  int sa = (int)csr[beg];
  uint4 rn = dimok ? *reinterpret_cast<const uint4*>(XLl + (size_t)sa * 64) : zero4();
  sa = (int)csr[beg + 1];
  for (int it = 0; it < mdeg; ++it) {
    const uint4 raw = rn;
    rn = dimok ? *reinterpret_cast<const uint4*>(XLl + (size_t)sa * 64) : zero4();
    sa = (int)csr[beg + it + 2];
    f32x2 xl2[4];
    unp8(raw, xl2);
    f32x2 pacc = (f32x2){0.f, 0.f};
#pragma unroll
    for (int j = 0; j < 4; ++j) {
      const f32x2 t = xl2[j] + xr2[j];
      const f32x2 lr = pk_max(t, t * ns);
      pacc = pk_fma(lr, a2[j], pacc);
    }
    float p = pacc[0] + pacc[1];
    p += __shfl_xor(p, 1, 64);
    p += __shfl_xor(p, 2, 64);
    p += __shfl_xor(p, 4, 64);      // group-uniform logit
    const float w = (it < deg) ? __expf(p) : 0.f;
    D += w;
    const f32x2 w2 = (f32x2){w, w};
#pragma unroll
    for (int j = 0; j < 4; ++j) A2[j] = pk_fma(w2, xl2[j], A2[j]);
  }
  if (gid >= NN) return;
  // ---- epilogue: each lane owns dims 8l..8l+7 of node d ----
  f32x2 xlin2[4];
  unp8(xlin_raw, xlin2);
  const float inv = 1.0f / D;  // D > 0 (self-loop); group-uniform
  float val[8];
#pragma unroll
  for (int j = 0; j < 8; ++j)
    val[j] = fmaf(A2[j >> 1][j & 1], inv, b[j]) + xlin2[j >> 1][j & 1];
  if (!FINAL) {
    uint4 o;
    o.x = pack2(fmaxf(val[0], 0.f), fmaxf(val[1], 0.f));
    o.y = pack2(fmaxf(val[2], 0.f), fmaxf(val[3], 0.f));
    o.z = pack2(fmaxf(val[4], 0.f), fmaxf(val[5], 0.f));
    o.w = pack2(fmaxf(val[6], 0.f), fmaxf(val[7], 0.f));
    *reinterpret_cast<uint4*>(&outb[(size_t)d * 64 + 8 * l]) = o;  // all lanes
  } else {
    float mx = -3e38f;
    if (dimok) {
#pragma unroll
      for (int j = 0; j < 8; ++j) mx = fmaxf(mx, val[j]);
    }
    mx = fmaxf(mx, __shfl_xor(mx, 1, 64));
    mx = fmaxf(mx, __shfl_xor(mx, 2, 64));
    mx = fmaxf(mx, __shfl_xor(mx, 4, 64));
    float es = 0.f;
    if (dimok) {
#pragma unroll
      for (int j = 0; j < 8; ++j) es += __expf(val[j] - mx);
    }
    es += __shfl_xor(es, 1, 64);
    es += __shfl_xor(es, 2, 64);
    es += __shfl_xor(es, 4, 64);
    const float lse = mx + __logf(es);
    if (dimok) {
      float4 o0, o1;
      o0.x = val[0] - lse; o0.y = val[1] - lse; o0.z = val[2] - lse; o0.w = val[3] - lse;
      o1.x = val[4] - lse; o1.y = val[5] - lse; o1.z = val[6] - lse; o1.w = val[7] - lse;
      float* dst = &out[(size_t)d * OC + 8 * l];
      *reinterpret_cast<float4*>(dst) = o0;
      *reinterpret_cast<float4*>(dst + 4) = o1;
    }
  }
}

// ---------------- launch ----------------
extern "C" void kernel_launch(void* const* d_in, const int* in_sizes, int n_in,
                              void* d_out, int out_size, void* d_ws, size_t ws_size,
                              hipStream_t stream) {
  const float* x     = (const float*)d_in[0];
  const int*   ei    = (const int*)d_in[1];
  const float* W1l   = (const float*)d_in[2];
  const float* b1l   = (const float*)d_in[3];
  const float* W1r   = (const float*)d_in[4];
  const float* b1r   = (const float*)d_in[5];
  const float* att1  = (const float*)d_in[6];
  const float* bias1 = (const float*)d_in[7];
  const float* lin1W = (const float*)d_in[8];
  const float* lin1b = (const float*)d_in[9];
  const float* W2l   = (const float*)d_in[10];
  const float* b2l   = (const float*)d_in[11];
  const float* W2r   = (const float*)d_in[12];
  const float* b2r   = (const float*)d_in[13];
  const float* att2  = (const float*)d_in[14];
  const float* bias2 = (const float*)d_in[15];
  const float* lin2W = (const float*)d_in[16];
  const float* lin2b = (const float*)d_in[17];
  float* out = (float*)d_out;

  char* ws = (char*)d_ws;
  size_t off = 0;
  auto alloc = [&](size_t bytes) -> void* {
    void* p = ws + off;
    off += (bytes + 255) & ~(size_t)255;
    return p;
  };
  short* Wp1 = (short*)alloc((size_t)TB1 * 2);
  short* Wp2 = (short*)alloc((size_t)TB2 * 2);
  unsigned short* XL1   = (unsigned short*)alloc((size_t)NN * 64 * 2);
  unsigned short* XR1   = (unsigned short*)alloc((size_t)NN * 64 * 2);
  unsigned short* XLIN1 = (unsigned short*)alloc((size_t)NN * 64 * 2);
  unsigned short* Hb    = (unsigned short*)alloc((size_t)NP * 64 * 2);
  unsigned short* XL2   = (unsigned short*)alloc((size_t)NN * 64 * 2);
  unsigned short* XR2   = (unsigned short*)alloc((size_t)NN * 64 * 2);
  unsigned short* XLIN2 = (unsigned short*)alloc((size_t)NN * 64 * 2);
  int* gcur    = (int*)alloc((size_t)NBKT * 4);
  int* offsets = (int*)alloc((size_t)(NN + 1) * 4);
  unsigned* rec = (unsigned*)alloc((size_t)NBKT * BCAP * 4);
  unsigned short* csr = (unsigned short*)alloc((size_t)(NITEMS + 8) * 2);

  hipMemsetAsync(gcur, 0, (size_t)NBKT * 4, stream);
  prep_bin<<<WPB + NCH, 256, 0, stream>>>(W1l, W1r, lin1W, W2l, W2r, lin2W,
                                          Wp1, Wp2, ei, out + (size_t)NN * CD,
                                          gcur, rec);
  build_gemm1<<<GB1 + NBKT, 256, 0, stream>>>(x, Wp1, b1l, b1r, lin1b,
                                              XL1, XR1, XLIN1, gcur, rec,
                                              offsets, csr);
  const int AGG_BLOCKS = (NN / 8 + 3) / 4;  // 4 waves/block, 8 nodes/wave
  gat_agg<64, false><<<AGG_BLOCKS, 256, 0, stream>>>(XL1, XR1, XLIN1, att1,
                                                     bias1, offsets, csr,
                                                     nullptr, Hb);
  gemm2<<<GB1, 256, 0, stream>>>((const short*)Hb, Wp2, b2l, b2r, lin2b,
                                 XL2, XR2, XLIN2);
  gat_agg<40, true><<<AGG_BLOCKS, 256, 0, stream>>>(XL2, XR2, XLIN2, att2,
                                                    bias2, offsets, csr,
                                                    out, nullptr);
}

// Round 8
// 226.746 us; speedup vs baseline: 1.0902x; 1.0902x over previous
//
#include <hip/hip_runtime.h>
#include <cmath>

#define NN 50000
#define NP 50048
#define NE 800000
#define CD 40
#define NEG_SLOPE 0.2f
#define NITEMS (NE + NN)   // edges + self-loops
#define CHUNK 2048
#define NCH 416            // ceil(NITEMS / CHUNK)
#define NBKT 391           // node buckets of 128 (covers 50048)
#define BCAP 3072          // bucket capacity (mean 2174, +19 sigma)
#define GB1 782            // gemm blocks, 64 rows each (NP/64)
#define TB1 (3 * 64 * 256)
#define TB2 (3 * 64 * 64)
#define WPB 240            // W-pack blocks ((TB1+TB2)/256)

typedef __attribute__((ext_vector_type(8))) short s16x8;   // 8 bf16
typedef __attribute__((ext_vector_type(4))) float f32x4;   // 4 fp32 acc
typedef __attribute__((ext_vector_type(2))) float f32x2;   // packed-math pair

__device__ __forceinline__ f32x2 pk_fma(f32x2 a, f32x2 b, f32x2 c) {
#if __has_builtin(__builtin_elementwise_fma)
  return __builtin_elementwise_fma(a, b, c);
#else
  f32x2 r; r[0] = fmaf(a[0], b[0], c[0]); r[1] = fmaf(a[1], b[1], c[1]); return r;
#endif
}
__device__ __forceinline__ f32x2 pk_max(f32x2 a, f32x2 b) {
#if __has_builtin(__builtin_elementwise_max)
  return __builtin_elementwise_max(a, b);
#else
  f32x2 r; r[0] = fmaxf(a[0], b[0]); r[1] = fmaxf(a[1], b[1]); return r;
#endif
}

__device__ __forceinline__ short f2bf(float x) {  // RNE, finite
  unsigned u = __builtin_bit_cast(unsigned, x);
  u += 0x7fffu + ((u >> 16) & 1u);
  return (short)(u >> 16);
}
__device__ __forceinline__ unsigned pack2(float lo, float hi) {
  return (unsigned)(unsigned short)f2bf(lo) | ((unsigned)(unsigned short)f2bf(hi) << 16);
}
__device__ __forceinline__ float bf2f_lo(unsigned v) {
  return __builtin_bit_cast(float, v << 16);
}
__device__ __forceinline__ float bf2f_hi(unsigned v) {
  return __builtin_bit_cast(float, v & 0xffff0000u);
}
__device__ __forceinline__ void unp8(uint4 v, f32x2* f) {
  f[0] = (f32x2){bf2f_lo(v.x), bf2f_hi(v.x)};
  f[1] = (f32x2){bf2f_lo(v.y), bf2f_hi(v.y)};
  f[2] = (f32x2){bf2f_lo(v.z), bf2f_hi(v.z)};
  f[3] = (f32x2){bf2f_lo(v.w), bf2f_hi(v.w)};
}
__device__ __forceinline__ uint4 zero4() {
  uint4 z; z.x = 0u; z.y = 0u; z.z = 0u; z.w = 0u; return z;
}

// ====== prep_bin: W frag-pack (blocks 0..239) | edge binning (blocks 240..) ======
__global__ __launch_bounds__(256) void prep_bin(const float* __restrict__ W1l,
                                                const float* __restrict__ W1r,
                                                const float* __restrict__ L1,
                                                const float* __restrict__ W2l,
                                                const float* __restrict__ W2r,
                                                const float* __restrict__ L2,
                                                short* __restrict__ Wp1,
                                                short* __restrict__ Wp2,
                                                const int* __restrict__ ei,
                                                float* __restrict__ outE,
                                                int* __restrict__ gcur,
                                                unsigned* __restrict__ rec) {
  const int tid = threadIdx.x;
  if (blockIdx.x < WPB) {  // W pack: [kb][w][t][lane][j]
    int e = blockIdx.x * 256 + tid;
    if (e < TB1) {  // layer 1: K=256, OC=64, src [256][64]
      int kb = e / 6144, r = e % 6144;
      int w = r / 2048, r2 = r % 2048;
      int t = r2 / 512, r3 = r2 % 512;
      int lane = r3 / 8, j = r3 % 8;
      int n = t * 16 + (lane & 15);
      int k = kb * 32 + (lane >> 4) * 8 + j;
      const float* W = (w == 0) ? W1l : (w == 1) ? W1r : L1;
      Wp1[e] = f2bf(W[k * 64 + n]);
    } else {  // layer 2: K=64, OC=40 pad 64
      e -= TB1;
      int kb = e / 6144, r = e % 6144;
      int w = r / 2048, r2 = r % 2048;
      int t = r2 / 512, r3 = r2 % 512;
      int lane = r3 / 8, j = r3 % 8;
      int n = t * 16 + (lane & 15);
      int k = kb * 32 + (lane >> 4) * 8 + j;
      const float* W = (w == 0) ? W2l : (w == 1) ? W2r : L2;
      Wp2[e] = (n < 40) ? f2bf(W[k * 40 + n]) : (short)0;
    }
    return;
  }
  // ---- Phase A ----
  __shared__ unsigned sorted[CHUNK];
  __shared__ int hist[512];
  __shared__ int bcur[512];
  __shared__ int gbase[512];
  const int base = (blockIdx.x - WPB) * CHUNK;
  for (int t = tid; t < 512; t += 256) { hist[t] = 0; bcur[t] = 0; gbase[t] = 0; }
  __syncthreads();
  unsigned key[CHUNK / 256];
#pragma unroll
  for (int u = 0; u < CHUNK / 256; ++u) {
    const int j = base + u * 256 + tid;
    unsigned k = 0xFFFFFFFFu;
    if (j < NITEMS) {
      int s, d;
      if (j < NE) {
        s = ei[j]; d = ei[NE + j];
        outE[j] = (float)s; outE[NE + j] = (float)d;
      } else {
        s = j - NE; d = s;
      }
      k = ((unsigned)d << 16) | (unsigned)s;
      atomicAdd(&hist[k >> 23], 1);
    }
    key[u] = k;
  }
  __syncthreads();
  if (tid < 64) {  // exclusive scan hist[0..511], one wave
    int carry = 0;
#pragma unroll
    for (int c = 0; c < 8; ++c) {
      int v = hist[c * 64 + tid];
      int inc = v;
#pragma unroll
      for (int off = 1; off < 64; off <<= 1) {
        int tt = __shfl_up(inc, off, 64);
        if (tid >= off) inc += tt;
      }
      hist[c * 64 + tid] = carry + inc - v;
      carry += __shfl(inc, 63, 64);
    }
  }
  __syncthreads();
#pragma unroll
  for (int u = 0; u < CHUNK / 256; ++u) {
    const unsigned k = key[u];
    if (k != 0xFFFFFFFFu) {
      const int b = k >> 23;
      sorted[hist[b] + atomicAdd(&bcur[b], 1)] = k;
    }
  }
  __syncthreads();
  for (int t = tid; t < NBKT; t += 256) {
    const int c = bcur[t];
    if (c > 0) gbase[t] = atomicAdd(&gcur[t], c);
  }
  __syncthreads();
  const int cnt = min(CHUNK, NITEMS - base);
  for (int i = tid; i < cnt; i += 256) {
    const unsigned k = sorted[i];
    const int b = k >> 23;
    const int p = gbase[b] + (i - hist[b]);
    if (p < BCAP) rec[(size_t)b * BCAP + p] = k;
  }
}

// ================= gemm1 body: 64 rows/block, 16 rows/wave =================
// Round-2 form: fp32 A loads + f2bf repack + explicit one-kb-ahead prefetch.
// (Round-3's bf16 direct-A variant collapsed to 48 VGPR and de-pipelined:
// 166us at ~1% VALU/MFMA util. Do not remove the prefetch structure.)
__device__ __forceinline__ void gemm1_body(int bid, const float* __restrict__ X,
                                           const short* __restrict__ Wp,
                                           const float* __restrict__ B0,
                                           const float* __restrict__ B1,
                                           const float* __restrict__ B2,
                                           unsigned short* __restrict__ Y0,
                                           unsigned short* __restrict__ Y1,
                                           unsigned short* __restrict__ Y2) {
  const int lane = threadIdx.x & 63;
  const int wave = threadIdx.x >> 6;
  const int r0 = bid * 64 + wave * 16;
  const int m = lane & 15;
  const int q = lane >> 4;
  f32x4 acc[3][4] = {};
  const float* a0 = X + (size_t)min(r0 + m, NN - 1) * 256 + q * 8;
  const short* bp = Wp + lane * 8;
  float4 v0 = *reinterpret_cast<const float4*>(a0);
  float4 v1 = *reinterpret_cast<const float4*>(a0 + 4);
#pragma unroll
  for (int kb = 0; kb < 8; ++kb) {
    s16x8 bf[12];
#pragma unroll
    for (int i = 0; i < 12; ++i)  // 12 independent loads, batched
      bf[i] = *reinterpret_cast<const s16x8*>(bp + (size_t)(kb * 12 + i) * 512);
    s16x8 af;
    af[0] = f2bf(v0.x); af[1] = f2bf(v0.y); af[2] = f2bf(v0.z); af[3] = f2bf(v0.w);
    af[4] = f2bf(v1.x); af[5] = f2bf(v1.y); af[6] = f2bf(v1.z); af[7] = f2bf(v1.w);
    if (kb < 7) {  // prefetch next A step before the MFMA burst
      v0 = *reinterpret_cast<const float4*>(a0 + (kb + 1) * 32);
      v1 = *reinterpret_cast<const float4*>(a0 + (kb + 1) * 32 + 4);
    }
#pragma unroll
    for (int i = 0; i < 12; ++i)
      acc[i >> 2][i & 3] = __builtin_amdgcn_mfma_f32_16x16x32_bf16(
          af, bf[i], acc[i >> 2][i & 3], 0, 0, 0);
  }
#pragma unroll
  for (int w = 0; w < 3; ++w) {
    const float* B = (w == 0) ? B0 : (w == 1) ? B1 : B2;
    unsigned short* Y = (w == 0) ? Y0 : (w == 1) ? Y1 : Y2;
#pragma unroll
    for (int t = 0; t < 4; ++t) {
      const int c = t * 16 + m;
      const float bv = B[c];
#pragma unroll
      for (int rg = 0; rg < 4; ++rg) {
        const int row = r0 + q * 4 + rg;
        if (row < NN)
          Y[(size_t)row * 64 + c] = (unsigned short)f2bf(acc[w][t][rg] + bv);
      }
    }
  }
}

// ====== build_gemm1: gemm1 (blocks 0..781) | CSR Phase B (blocks 782..1172) ======
// launch_bounds (256,3): gemm phase is L2-latency bound at 2 waves/SIMD;
// fits without spill, +50% latency hiding (round-5 verified, part of -10us).
__global__ __launch_bounds__(256, 3) void build_gemm1(
    const float* __restrict__ X, const short* __restrict__ Wp1,
    const float* __restrict__ B0, const float* __restrict__ B1,
    const float* __restrict__ B2, unsigned short* __restrict__ Y0,
    unsigned short* __restrict__ Y1, unsigned short* __restrict__ Y2,
    const int* __restrict__ gcur, const unsigned* __restrict__ rec,
    int* __restrict__ offsets, unsigned short* __restrict__ csr16) {
  if (blockIdx.x < GB1) {
    gemm1_body(blockIdx.x, X, Wp1, B0, B1, B2, Y0, Y1, Y2);
    return;
  }
  const int b = blockIdx.x - GB1;
  const int tid = threadIdx.x;
  __shared__ unsigned recs[BCAP];
  __shared__ int red[256];
  __shared__ int cnt[128];
  __shared__ int sc[128];
  __shared__ int cur[128];
  int acc = 0;
  for (int t = tid; t < NBKT; t += 256)
    if (t < b) acc += gcur[t];
  red[tid] = acc;
  __syncthreads();
#pragma unroll
  for (int off = 128; off >= 1; off >>= 1) {
    if (tid < off) red[tid] += red[tid + off];
    __syncthreads();
  }
  const int base = red[0];
  const int Tb = min(gcur[b], BCAP);
  if (tid < 128) cnt[tid] = 0;
  __syncthreads();
  for (int i = tid; i < Tb; i += 256) {
    const unsigned k = rec[(size_t)b * BCAP + i];
    recs[i] = k;
    atomicAdd(&cnt[(k >> 16) & 127], 1);
  }
  __syncthreads();
  if (tid < 128) sc[tid] = cnt[tid];
  __syncthreads();
#pragma unroll
  for (int off = 1; off < 128; off <<= 1) {
    int v = (tid < 128 && tid >= off) ? sc[tid - off] : 0;
    __syncthreads();
    if (tid < 128) sc[tid] += v;
    __syncthreads();
  }
  if (tid < 128) {
    const int n = b * 128 + tid;
    if (n < NN) offsets[n + 1] = base + sc[tid];
    cur[tid] = sc[tid] - cnt[tid];
  }
  if (b == 0 && tid == 0) {
    offsets[0] = 0;
#pragma unroll
    for (int i = 0; i < 8; ++i) csr16[NITEMS + i] = 0;  // pad: agg reads 2 ahead
  }
  __syncthreads();
  for (int i = tid; i < Tb; i += 256) {
    const unsigned k = recs[i];
    const int p = atomicAdd(&cur[(k >> 16) & 127], 1);
    csr16[base + p] = (unsigned short)(k & 0xFFFFu);
  }
}

// ============ gemm2: Hb bf16 [NP][64] @ Wp2, 64 rows/block ============
__global__ __launch_bounds__(256, 2) void gemm2(const short* __restrict__ Xb,
                                                const short* __restrict__ Wp,
                                                const float* __restrict__ B0,
                                                const float* __restrict__ B1,
                                                const float* __restrict__ B2,
                                                unsigned short* __restrict__ Y0,
                                                unsigned short* __restrict__ Y1,
                                                unsigned short* __restrict__ Y2) {
  const int lane = threadIdx.x & 63;
  const int wave = threadIdx.x >> 6;
  const int r0 = blockIdx.x * 64 + wave * 16;
  const int m = lane & 15;
  const int q = lane >> 4;
  f32x4 acc[3][3] = {};
  const short* a0 = Xb + (size_t)(r0 + m) * 64 + q * 8;
  const short* bp = Wp + lane * 8;
#pragma unroll
  for (int kb = 0; kb < 2; ++kb) {
    s16x8 bf[9];
#pragma unroll
    for (int w = 0; w < 3; ++w)
#pragma unroll
      for (int t = 0; t < 3; ++t)
        bf[w * 3 + t] =
            *reinterpret_cast<const s16x8*>(bp + (size_t)(kb * 12 + w * 4 + t) * 512);
    const s16x8 af = *reinterpret_cast<const s16x8*>(a0 + kb * 32);
#pragma unroll
    for (int w = 0; w < 3; ++w)
#pragma unroll
      for (int t = 0; t < 3; ++t)
        acc[w][t] = __builtin_amdgcn_mfma_f32_16x16x32_bf16(af, bf[w * 3 + t],
                                                            acc[w][t], 0, 0, 0);
  }
#pragma unroll
  for (int w = 0; w < 3; ++w) {
    const float* B = (w == 0) ? B0 : (w == 1) ? B1 : B2;
    unsigned short* Y = (w == 0) ? Y0 : (w == 1) ? Y1 : Y2;
#pragma unroll
    for (int t = 0; t < 3; ++t) {
      const int c = t * 16 + m;
      if (c < 40) {
        const float bv = B[c];
#pragma unroll
        for (int rg = 0; rg < 4; ++rg) {
          const int row = r0 + q * 4 + rg;
          if (row < NN)
            Y[(size_t)row * 64 + c] = (unsigned short)f2bf(acc[w][t][rg] + bv);
        }
      }
    }
  }
}

// ====== GATv2 aggregation: 8 NODES per wave (round-5 verified form) ======
// Group g owns node gid (sequential -> coalesced per-node I/O). Per-lane A2
// is the complete sum for its node's dims; no cross-group merge. csr padded
// (+8) so the 2-ahead index prefetch needs no clamps. Single-edge/iter
// pipeline: round-6's 2-edge MLP variant regressed; round-7's reg hoists
// also did not beat this form. Byte-identical A/A rerun of the 227.0us
// round-5 config to pin the noise band.
template <int OC, bool FINAL>
__global__ __launch_bounds__(256) void gat_agg(const unsigned short* __restrict__ XL,
                                               const unsigned short* __restrict__ XR,
                                               const unsigned short* __restrict__ XLIN,
                                               const float* __restrict__ att,
                                               const float* __restrict__ bias,
                                               const int* __restrict__ offsets,
                                               const unsigned short* __restrict__ csr,
                                               float* __restrict__ out,
                                               unsigned short* __restrict__ outb) {
  const int lane = threadIdx.x & 63;
  const int g = lane >> 3;          // node slot within wave
  const int l = lane & 7;           // dim slot (dims 8l..8l+7)
  const int wv = threadIdx.x >> 6;
  const int gid = (blockIdx.x * 4 + wv) * 8 + g;
  const int d = min(gid, NN - 1);
  constexpr bool FULLW = (OC >= 64);
  const bool dimok = FULLW || (8 * l < OC);

  const int beg = offsets[d];
  int end = offsets[d + 1];
  if (gid >= NN) end = beg;         // dead slots: zero iterations
  const int deg = end - beg;
  int mdeg = deg;                   // wave-max degree = loop bound
  mdeg = max(mdeg, __shfl_xor(mdeg, 8, 64));
  mdeg = max(mdeg, __shfl_xor(mdeg, 16, 64));
  mdeg = max(mdeg, __shfl_xor(mdeg, 32, 64));

  f32x2 a2[4] = {};
  if (dimok) {
    const float4 t0 = *reinterpret_cast<const float4*>(&att[8 * l]);
    const float4 t1 = *reinterpret_cast<const float4*>(&att[8 * l + 4]);
    a2[0] = (f32x2){t0.x, t0.y}; a2[1] = (f32x2){t0.z, t0.w};
    a2[2] = (f32x2){t1.x, t1.y}; a2[3] = (f32x2){t1.z, t1.w};
  }
  f32x2 xr2[4];
  unp8(dimok ? *reinterpret_cast<const uint4*>(XR + (size_t)d * 64 + 8 * l) : zero4(),
       xr2);

  const unsigned short* XLl = XL + 8 * l;
  float D = 0.f;
  f32x2 A2[4] = {};
  const f32x2 ns = (f32x2){NEG_SLOPE, NEG_SLOPE};
  // pipeline: data one ahead, index two ahead (padded csr, no clamps)
  int sa = (int)csr[beg];
  uint4 rn = dimok ? *reinterpret_cast<const uint4*>(XLl + (size_t)sa * 64) : zero4();
  sa = (int)csr[beg + 1];
  for (int it = 0; it < mdeg; ++it) {
    const uint4 raw = rn;
    rn = dimok ? *reinterpret_cast<const uint4*>(XLl + (size_t)sa * 64) : zero4();
    sa = (int)csr[beg + it + 2];
    f32x2 xl2[4];
    unp8(raw, xl2);
    f32x2 pacc = (f32x2){0.f, 0.f};
#pragma unroll
    for (int j = 0; j < 4; ++j) {
      const f32x2 t = xl2[j] + xr2[j];
      const f32x2 lr = pk_max(t, t * ns);
      pacc = pk_fma(lr, a2[j], pacc);
    }
    float p = pacc[0] + pacc[1];
    p += __shfl_xor(p, 1, 64);
    p += __shfl_xor(p, 2, 64);
    p += __shfl_xor(p, 4, 64);      // group-uniform logit
    const float w = (it < deg) ? __expf(p) : 0.f;
    D += w;
    const f32x2 w2 = (f32x2){w, w};
#pragma unroll
    for (int j = 0; j < 4; ++j) A2[j] = pk_fma(w2, xl2[j], A2[j]);
  }
  if (gid >= NN) return;
  // ---- epilogue: each lane owns dims 8l..8l+7 of node d ----
  f32x2 xlin2[4];
  unp8(dimok ? *reinterpret_cast<const uint4*>(XLIN + (size_t)d * 64 + 8 * l)
             : zero4(),
       xlin2);
  float b[8] = {};
  if (dimok) {
    const float4 t0 = *reinterpret_cast<const float4*>(&bias[8 * l]);
    const float4 t1 = *reinterpret_cast<const float4*>(&bias[8 * l + 4]);
    b[0] = t0.x; b[1] = t0.y; b[2] = t0.z; b[3] = t0.w;
    b[4] = t1.x; b[5] = t1.y; b[6] = t1.z; b[7] = t1.w;
  }
  const float inv = 1.0f / D;  // D > 0 (self-loop); group-uniform
  float val[8];
#pragma unroll
  for (int j = 0; j < 8; ++j)
    val[j] = fmaf(A2[j >> 1][j & 1], inv, b[j]) + xlin2[j >> 1][j & 1];
  if (!FINAL) {
    uint4 o;
    o.x = pack2(fmaxf(val[0], 0.f), fmaxf(val[1], 0.f));
    o.y = pack2(fmaxf(val[2], 0.f), fmaxf(val[3], 0.f));
    o.z = pack2(fmaxf(val[4], 0.f), fmaxf(val[5], 0.f));
    o.w = pack2(fmaxf(val[6], 0.f), fmaxf(val[7], 0.f));
    *reinterpret_cast<uint4*>(&outb[(size_t)d * 64 + 8 * l]) = o;  // all lanes
  } else {
    float mx = -3e38f;
    if (dimok) {
#pragma unroll
      for (int j = 0; j < 8; ++j) mx = fmaxf(mx, val[j]);
    }
    mx = fmaxf(mx, __shfl_xor(mx, 1, 64));
    mx = fmaxf(mx, __shfl_xor(mx, 2, 64));
    mx = fmaxf(mx, __shfl_xor(mx, 4, 64));
    float es = 0.f;
    if (dimok) {
#pragma unroll
      for (int j = 0; j < 8; ++j) es += __expf(val[j] - mx);
    }
    es += __shfl_xor(es, 1, 64);
    es += __shfl_xor(es, 2, 64);
    es += __shfl_xor(es, 4, 64);
    const float lse = mx + __logf(es);
    if (dimok) {
      float4 o0, o1;
      o0.x = val[0] - lse; o0.y = val[1] - lse; o0.z = val[2] - lse; o0.w = val[3] - lse;
      o1.x = val[4] - lse; o1.y = val[5] - lse; o1.z = val[6] - lse; o1.w = val[7] - lse;
      float* dst = &out[(size_t)d * OC + 8 * l];
      *reinterpret_cast<float4*>(dst) = o0;
      *reinterpret_cast<float4*>(dst + 4) = o1;
    }
  }
}

// ---------------- launch ----------------
extern "C" void kernel_launch(void* const* d_in, const int* in_sizes, int n_in,
                              void* d_out, int out_size, void* d_ws, size_t ws_size,
                              hipStream_t stream) {
  const float* x     = (const float*)d_in[0];
  const int*   ei    = (const int*)d_in[1];
  const float* W1l   = (const float*)d_in[2];
  const float* b1l   = (const float*)d_in[3];
  const float* W1r   = (const float*)d_in[4];
  const float* b1r   = (const float*)d_in[5];
  const float* att1  = (const float*)d_in[6];
  const float* bias1 = (const float*)d_in[7];
  const float* lin1W = (const float*)d_in[8];
  const float* lin1b = (const float*)d_in[9];
  const float* W2l   = (const float*)d_in[10];
  const float* b2l   = (const float*)d_in[11];
  const float* W2r   = (const float*)d_in[12];
  const float* b2r   = (const float*)d_in[13];
  const float* att2  = (const float*)d_in[14];
  const float* bias2 = (const float*)d_in[15];
  const float* lin2W = (const float*)d_in[16];
  const float* lin2b = (const float*)d_in[17];
  float* out = (float*)d_out;

  char* ws = (char*)d_ws;
  size_t off = 0;
  auto alloc = [&](size_t bytes) -> void* {
    void* p = ws + off;
    off += (bytes + 255) & ~(size_t)255;
    return p;
  };
  short* Wp1 = (short*)alloc((size_t)TB1 * 2);
  short* Wp2 = (short*)alloc((size_t)TB2 * 2);
  unsigned short* XL1   = (unsigned short*)alloc((size_t)NN * 64 * 2);
  unsigned short* XR1   = (unsigned short*)alloc((size_t)NN * 64 * 2);
  unsigned short* XLIN1 = (unsigned short*)alloc((size_t)NN * 64 * 2);
  unsigned short* Hb    = (unsigned short*)alloc((size_t)NP * 64 * 2);
  unsigned short* XL2   = (unsigned short*)alloc((size_t)NN * 64 * 2);
  unsigned short* XR2   = (unsigned short*)alloc((size_t)NN * 64 * 2);
  unsigned short* XLIN2 = (unsigned short*)alloc((size_t)NN * 64 * 2);
  int* gcur    = (int*)alloc((size_t)NBKT * 4);
  int* offsets = (int*)alloc((size_t)(NN + 1) * 4);
  unsigned* rec = (unsigned*)alloc((size_t)NBKT * BCAP * 4);
  unsigned short* csr = (unsigned short*)alloc((size_t)(NITEMS + 8) * 2);

  hipMemsetAsync(gcur, 0, (size_t)NBKT * 4, stream);
  prep_bin<<<WPB + NCH, 256, 0, stream>>>(W1l, W1r, lin1W, W2l, W2r, lin2W,
                                          Wp1, Wp2, ei, out + (size_t)NN * CD,
                                          gcur, rec);
  build_gemm1<<<GB1 + NBKT, 256, 0, stream>>>(x, Wp1, b1l, b1r, lin1b,
                                              XL1, XR1, XLIN1, gcur, rec,
                                              offsets, csr);
  const int AGG_BLOCKS = (NN / 8 + 3) / 4;  // 4 waves/block, 8 nodes/wave
  gat_agg<64, false><<<AGG_BLOCKS, 256, 0, stream>>>(XL1, XR1, XLIN1, att1,
                                                     bias1, offsets, csr,
                                                     nullptr, Hb);
  gemm2<<<GB1, 256, 0, stream>>>((const short*)Hb, Wp2, b2l, b2r, lin2b,
                                 XL2, XR2, XLIN2);
  gat_agg<40, true><<<AGG_BLOCKS, 256, 0, stream>>>(XL2, XR2, XLIN2, att2,
                                                    bias2, offsets, csr,
                                                    out, nullptr);
}